// Round 6
// baseline (376.800 us; speedup 1.0000x reference)
//
#include <hip/hip_runtime.h>
#include <hip/hip_bf16.h>

#define BB 2
#define NQ 2048
#define NCTX 2048
#define DIMM 1024
#define NH 16
#define DH 64
#define NKV 4096
#define LOG2E 1.44269504088896340736f

typedef float f32x4  __attribute__((ext_vector_type(4)));
typedef float f32x16 __attribute__((ext_vector_type(16)));
typedef short s16x8  __attribute__((ext_vector_type(8)));
typedef unsigned u32x4 __attribute__((ext_vector_type(4)));

__device__ __forceinline__ unsigned short f2bf(float f){
  __hip_bfloat16 h = __float2bfloat16(f);
  return *reinterpret_cast<unsigned short*>(&h);
}

// v_cvt_pk_bf16_f32: D.lo16 = bf16(a), D.hi16 = bf16(b) (RNE), HW-verified R5
__device__ __forceinline__ unsigned pk2(float a, float b){
  unsigned r;
  asm("v_cvt_pk_bf16_f32 %0, %1, %2" : "=v"(r) : "v"(a), "v"(b));
  return r;
}

// async global->LDS, 16B per lane; LDS base must be wave-uniform
__device__ __forceinline__ void cp16(const void* g, void* l){
  __builtin_amdgcn_global_load_lds(
    (const __attribute__((address_space(1))) unsigned int*)(unsigned long long)g,
    (__attribute__((address_space(3))) unsigned int*)(unsigned int)(unsigned long long)l,
    16, 0, 0);
}

__device__ __forceinline__ f32x16 zero16(){
  f32x16 z;
  #pragma unroll
  for (int i=0;i<16;i++) z[i]=0.f;
  return z;
}

// ---------------- merged LayerNorm (x rows then ctx rows) ----------------
__global__ __launch_bounds__(256) void ln2_kernel(const float* __restrict__ x,
    const float* __restrict__ ctx,
    const float* __restrict__ g1, const float* __restrict__ b1,
    const float* __restrict__ g2, const float* __restrict__ b2,
    unsigned short* __restrict__ xn, unsigned short* __restrict__ cn){
  int row = blockIdx.x;
  const float *src, *g, *bta; unsigned short* dst; int r;
  if (row < BB*NQ){ src = x;   g = g1; bta = b1; dst = xn; r = row; }
  else            { src = ctx; g = g2; bta = b2; dst = cn; r = row - BB*NQ; }
  int t = threadIdx.x;
  const float4* xr = (const float4*)(src + (size_t)r*DIMM);
  float4 v = xr[t];
  float s  = v.x+v.y+v.z+v.w;
  float sq = v.x*v.x+v.y*v.y+v.z*v.z+v.w*v.w;
  #pragma unroll
  for (int off=32; off>0; off>>=1){ s += __shfl_down(s, off); sq += __shfl_down(sq, off); }
  __shared__ float red[8];
  int w = t>>6;
  if ((t&63)==0){ red[w]=s; red[w+4]=sq; }
  __syncthreads();
  s  = red[0]+red[1]+red[2]+red[3];
  sq = red[4]+red[5]+red[6]+red[7];
  float mean = s*(1.0f/DIMM);
  float var  = sq*(1.0f/DIMM) - mean*mean;
  float rstd = rsqrtf(var + 1e-5f);
  float4 gv = ((const float4*)g)[t];
  float4 bv = ((const float4*)bta)[t];
  unsigned int o0 = f2bf((v.x-mean)*rstd*gv.x + bv.x);
  unsigned int o1 = f2bf((v.y-mean)*rstd*gv.y + bv.y);
  unsigned int o2 = f2bf((v.z-mean)*rstd*gv.z + bv.z);
  unsigned int o3 = f2bf((v.w-mean)*rstd*gv.w + bv.w);
  uint2 pk; pk.x = o0 | (o1<<16); pk.y = o2 | (o3<<16);
  ((uint2*)(dst + (size_t)r*DIMM))[t] = pk;
}

// ---------- merged weight transpose+convert (Wq | Wkv | Wo) ----------
__global__ __launch_bounds__(256) void wconv3_kernel(const float* __restrict__ Wq,
    const float* __restrict__ Wkv, const float* __restrict__ Wo,
    unsigned short* __restrict__ wpk, unsigned short* __restrict__ woT){
  __shared__ float tile[32][33];
  int bx = blockIdx.x;                 // 0..127
  const float* src; unsigned short* dst; int N; float scale; int nb;
  if (bx < 32)      { src=Wq;  dst=wpk;                      N=1024; scale=0.125f; nb=bx; }
  else if (bx < 96) { src=Wkv; dst=wpk + (size_t)1024*1024;  N=2048; scale=1.0f;   nb=bx-32; }
  else              { src=Wo;  dst=woT;                      N=1024; scale=1.0f;   nb=bx-96; }
  int n0 = nb*32, k0 = blockIdx.y*32;
  int c = threadIdx.x & 31, r0 = threadIdx.x >> 5;
  #pragma unroll
  for (int i=0;i<4;i++){
    int r = r0 + i*8;
    tile[r][c] = src[(size_t)(k0+r)*N + n0 + c];
  }
  __syncthreads();
  #pragma unroll
  for (int i=0;i<4;i++){
    int r = r0 + i*8;
    dst[(size_t)(n0+r)*1024 + k0 + c] = f2bf(tile[c][r]*scale);
  }
}

// ---------------- bf16 GEMM: C = A[M][K] * BT[N][K]^T ----------------
#define BM 128
#define BN 128
#define BK 64
template<int MODE>
__global__ __launch_bounds__(256) void gemm_kernel(
    const unsigned short* __restrict__ A,
    const unsigned short* __restrict__ BT,
    unsigned short* __restrict__ D0,
    unsigned short* __restrict__ D1,
    unsigned short* __restrict__ D2,
    float* __restrict__ FO,
    const float* __restrict__ bias,
    int K){
  __shared__ unsigned short As[BM*BK];
  __shared__ unsigned short Bs[BN*BK];
  int t = threadIdx.x;
  int w = t>>6, l = t&63, lr = l&15, lg = l>>4;
  int wm = w>>1, wn = w&1;
  const unsigned short* Ab = A  + (size_t)(blockIdx.y*BM)*K;
  const unsigned short* Bb = BT + (size_t)(blockIdx.x*BN)*K;
  f32x4 acc[4][4];
  #pragma unroll
  for (int i=0;i<4;i++)
    #pragma unroll
    for (int j=0;j<4;j++) acc[i][j] = (f32x4){0.f,0.f,0.f,0.f};
  int nk = K >> 6;
  for (int kt=0; kt<nk; ++kt){
    __syncthreads();
    #pragma unroll
    for (int q=0;q<4;q++){
      int row = w*32 + q*8 + (l>>3);
      size_t go = (size_t)row*K + kt*64 + (l&7)*8;
      cp16(Ab + go, &As[(w*32+q*8)*64]);
      cp16(Bb + go, &Bs[(w*32+q*8)*64]);
    }
    __syncthreads();
    #pragma unroll
    for (int kk=0;kk<2;kk++){
      s16x8 af[4], bfr[4];
      #pragma unroll
      for (int mf=0;mf<4;mf++) af[mf]  = *(const s16x8*)&As[(wm*64+mf*16+lr)*64 + kk*32 + lg*8];
      #pragma unroll
      for (int nf=0;nf<4;nf++) bfr[nf] = *(const s16x8*)&Bs[(wn*64+nf*16+lr)*64 + kk*32 + lg*8];
      #pragma unroll
      for (int mf=0;mf<4;mf++)
        #pragma unroll
        for (int nf=0;nf<4;nf++)
          acc[mf][nf] = __builtin_amdgcn_mfma_f32_16x16x32_bf16(af[mf], bfr[nf], acc[mf][nf], 0,0,0);
    }
  }
  int rbase = blockIdx.y*BM + wm*64;
  int cbase = blockIdx.x*BN + wn*64;
  #pragma unroll
  for (int mf=0;mf<4;mf++){
    #pragma unroll
    for (int nf=0;nf<4;nf++){
      #pragma unroll
      for (int rr=0;rr<4;rr++){
        int r = rbase + mf*16 + lg*4 + rr;
        int c = cbase + nf*16 + lr;
        float val = acc[mf][nf][rr];
        if (MODE == 2){
          FO[(size_t)r*1024 + c] = val + bias[c];
        } else if (MODE == 0){
          int b = r >> 11, rl = r & 2047;
          unsigned short bv = f2bf(val);
          if (c < 1024)      D0[((size_t)b*NQ + rl)*1024 + c] = bv;
          else if (c < 2048) D1[((size_t)b*NKV + NCTX + rl)*1024 + (c-1024)] = bv;
          else               D2[((size_t)b*NKV + NCTX + rl)*1024 + (c-2048)] = bv;
        } else {
          int b = r >> 11, rl = r & 2047;
          unsigned short bv = f2bf(val);
          if (c < 1024) D0[((size_t)b*NKV + rl)*1024 + c] = bv;
          else          D1[((size_t)b*NKV + rl)*1024 + (c-1024)] = bv;
        }
      }
    }
  }
}

// ---------- V transpose: V[b][j][h*64+d] -> VT[(b*16+h)*64+d][j] (bf16) ----------
__global__ __launch_bounds__(256) void vtrans_kernel(const unsigned short* __restrict__ V,
    unsigned short* __restrict__ VT){
  __shared__ unsigned short tl[64][72];
  int j0 = blockIdx.x*64, h = blockIdx.y, b = blockIdx.z;
  int tid = threadIdx.x;
  int r = tid>>3, c8 = (tid&7)*8;
  const unsigned short* src = V + ((size_t)(b*NKV + j0))*1024 + h*64;
  #pragma unroll
  for (int p=0;p<2;p++){
    int row = r + p*32;
    *(s16x8*)&tl[row][c8] = *(const s16x8*)(src + (size_t)row*1024 + c8);
  }
  __syncthreads();
  unsigned short* dst = VT + ((size_t)(b*16+h)*64)*4096 + j0;
  #pragma unroll
  for (int p=0;p<2;p++){
    int d = r + p*32;
    s16x8 o;
    #pragma unroll
    for (int e=0;e<8;e++) o[e] = (short)tl[c8+e][d];
    *(s16x8*)(dst + (size_t)d*4096 + c8) = o;
  }
}

// ---------------- flash attention (causal-prefix), 32x32 swapped-QK ----------------
// R6: KVBLK=128, LDS double-buffer (1 barrier/tile), reg prefetch 1 full tile ahead.
// Fragment algebra / swizzle / T12 packing identical to R5 (HW-proven), slice t ->
// array s[t>>1], half B8=(t&1)*8; V sub-buffers Va (j 0..63), Vb2 (j 64..127).
__global__ __launch_bounds__(256) void attn_kernel(
    const unsigned short* __restrict__ Q,
    const unsigned short* __restrict__ Kg,
    const unsigned short* __restrict__ VT,
    unsigned short* __restrict__ O){
  __shared__ unsigned short Ks[2][128*64];   // [j][d] swizzled, 16KB each
  __shared__ unsigned short Va[2][64*64];    // [d][j0..63] swizzled
  __shared__ unsigned short Vb2[2][64*64];   // [d][j64..127] swizzled
  int bx = blockIdx.x;
  int qb = 15 - (bx >> 5);          // longest (most KV tiles) first
  int hb = bx & 31;
  int h = hb & 15, b = hb >> 4;
  int i0 = qb*128;
  int tid = threadIdx.x;
  int w = tid>>6, l = tid&63;
  int q5 = l&31, hi = l>>5;

  int row0 = tid>>3, sl = tid&7;    // staging: row0 0..31, sl 0..7
  const unsigned short* Kb  = Kg + (size_t)b*NKV*1024 + h*64;      // [j][1024]
  const unsigned short* Vbp = VT + ((size_t)(b*16+h)*64)*4096;     // [d][4096]
  int swz = (sl*16) ^ ((row0&7)<<4);

  const unsigned short* Qr = Q + ((size_t)(b*NQ + i0 + w*32 + q5))*1024 + h*64 + hi*8;
  s16x8 qf[4];
  #pragma unroll
  for (int t=0;t<4;t++) qf[t] = *(const s16x8*)(Qr + t*16);

  f32x16 o0 = zero16(), o1 = zero16();
  float mref = -1e30f, m2 = 0.f, lsum = 0.f;
  int nkb = 17 + qb;                // (NCTX + i0 + 128)/128

  // ---- prologue: stage tile 0 into buffer 0 ----
  #pragma unroll
  for (int i=0;i<4;i++){
    s16x8 kv = *(const s16x8*)(Kb + (size_t)(row0+32*i)*1024 + sl*8);
    *(s16x8*)((char*)Ks[0] + (row0+32*i)*128 + swz) = kv;
  }
  #pragma unroll
  for (int i=0;i<2;i++){
    s16x8 va = *(const s16x8*)(Vbp + (size_t)(row0+32*i)*4096 + sl*8);
    s16x8 vb = *(const s16x8*)(Vbp + (size_t)(row0+32*i)*4096 + 64 + sl*8);
    *(s16x8*)((char*)Va[0]  + (row0+32*i)*128 + swz) = va;
    *(s16x8*)((char*)Vb2[0] + (row0+32*i)*128 + swz) = vb;
  }
  __syncthreads();

  int p = 0;
  for (int kb=0; kb<nkb; ++kb){
    int j0 = kb*128;
    bool hn = (kb+1 < nkb);
    // ---- T14: issue next tile's global loads before compute ----
    s16x8 kr[4], vra[2], vrb[2];
    if (hn){
      int jn = j0 + 128;
      #pragma unroll
      for (int i=0;i<4;i++)
        kr[i] = *(const s16x8*)(Kb + (size_t)(jn + row0+32*i)*1024 + sl*8);
      #pragma unroll
      for (int i=0;i<2;i++){
        vra[i] = *(const s16x8*)(Vbp + (size_t)(row0+32*i)*4096 + jn + sl*8);
        vrb[i] = *(const s16x8*)(Vbp + (size_t)(row0+32*i)*4096 + jn + 64 + sl*8);
      }
    }

    // ---- QK^T (swapped): s[g] rows = keys j0+32g.., cols = q ----
    f32x16 s[4];
    #pragma unroll
    for (int g=0;g<4;g++) s[g] = zero16();
    __builtin_amdgcn_s_setprio(1);
    #pragma unroll
    for (int g=0;g<4;g++){
      #pragma unroll
      for (int t=0;t<4;t++){
        int xo = (t*32 + hi*16) ^ ((q5&7)<<4);
        s16x8 kf = *(const s16x8*)((char*)Ks[p] + (q5+32*g)*128 + xo);
        s[g] = __builtin_amdgcn_mfma_f32_32x32x16_bf16(kf, qf[t], s[g], 0,0,0);
      }
    }
    __builtin_amdgcn_s_setprio(0);

    // ---- causal-prefix mask ----
    if (j0 + 127 > NCTX + i0 + w*32){
      int iq = i0 + w*32 + q5;
      #pragma unroll
      for (int r=0;r<16;r++){
        int jj = j0 + ((r&3)+8*(r>>2)+4*hi);
        #pragma unroll
        for (int g=0;g<4;g++)
          if (jj + 32*g > NCTX + iq) s[g][r] = -1e30f;
      }
    }

    // ---- row max (4 parallel chains) ----
    float c0=-1e30f, c1=-1e30f, c2=-1e30f, c3=-1e30f;
    #pragma unroll
    for (int g=0;g<4;g++){
      #pragma unroll
      for (int r=0;r<16;r+=4){
        c0 = fmaxf(c0, s[g][r  ]);
        c1 = fmaxf(c1, s[g][r+1]);
        c2 = fmaxf(c2, s[g][r+2]);
        c3 = fmaxf(c3, s[g][r+3]);
      }
    }
    float pm = fmaxf(fmaxf(c0,c1), fmaxf(c2,c3));
    pm = fmaxf(pm, __shfl_xor(pm, 32));
    // ---- defer-max rescale (T13, THR=8) ----
    if (__any(pm - mref > 8.0f)){
      float mnew = fmaxf(mref, pm);
      float alpha = exp2f((mref - mnew)*LOG2E);
      mref = mnew; m2 = mnew*LOG2E;
      lsum *= alpha;
      int ai = __builtin_bit_cast(int, alpha);
      #pragma unroll
      for (int r=0;r<16;r++){
        int cr = (r&3)+8*(r>>2)+4*hi;
        float av = __builtin_bit_cast(float, __builtin_amdgcn_ds_bpermute(cr<<2, ai));
        o0[r] *= av; o1[r] *= av;
      }
    }
    // ---- exp, 4-way split accumulators ----
    float e0=0.f, e1=0.f, e2=0.f, e3=0.f;
    #pragma unroll
    for (int g=0;g<4;g++){
      #pragma unroll
      for (int r=0;r<16;r+=4){
        float a0 = exp2f(fmaf(s[g][r  ], LOG2E, -m2));
        float a1 = exp2f(fmaf(s[g][r+1], LOG2E, -m2));
        float a2 = exp2f(fmaf(s[g][r+2], LOG2E, -m2));
        float a3 = exp2f(fmaf(s[g][r+3], LOG2E, -m2));
        s[g][r]=a0; s[g][r+1]=a1; s[g][r+2]=a2; s[g][r+3]=a3;
        e0 += a0; e1 += a1; e2 += a2; e3 += a3;
      }
    }
    float ps = (e0+e1) + (e2+e3);
    ps += __shfl_xor(ps, 32);
    lsum += ps;

    // ---- T12 pack + PV (8 j-slices of 16) ----
    __builtin_amdgcn_s_setprio(1);
    #pragma unroll
    for (int t=0;t<8;t++){
      const f32x16& pp = s[t>>1];
      int B8 = (t&1)*8;
      unsigned u0 = pk2(pp[B8+0], pp[B8+1]);
      unsigned u1 = pk2(pp[B8+2], pp[B8+3]);
      unsigned v0 = pk2(pp[B8+4], pp[B8+5]);
      unsigned v1 = pk2(pp[B8+6], pp[B8+7]);
      asm("v_permlane32_swap_b32 %0, %1" : "+v"(u0), "+v"(v0));
      asm("v_permlane32_swap_b32 %0, %1" : "+v"(u1), "+v"(v1));
      s16x8 pa = __builtin_bit_cast(s16x8, (u32x4){u0, u1, v0, v1});
      const char* vsb = (t<4) ? (const char*)Va[p] : (const char*)Vb2[p];
      int tt = t&3;
      int xo = (tt*32 + hi*16) ^ ((q5&7)<<4);
      s16x8 vb0 = *(const s16x8*)(vsb + q5*128 + xo);
      s16x8 vb1 = *(const s16x8*)(vsb + (q5+32)*128 + xo);
      o0 = __builtin_amdgcn_mfma_f32_32x32x16_bf16(pa, vb0, o0, 0,0,0);
      o1 = __builtin_amdgcn_mfma_f32_32x32x16_bf16(pa, vb1, o1, 0,0,0);
    }
    __builtin_amdgcn_s_setprio(0);

    // ---- write next tile into the other buffer, single barrier ----
    if (hn){
      #pragma unroll
      for (int i=0;i<4;i++)
        *(s16x8*)((char*)Ks[p^1] + (row0+32*i)*128 + swz) = kr[i];
      #pragma unroll
      for (int i=0;i<2;i++){
        *(s16x8*)((char*)Va[p^1]  + (row0+32*i)*128 + swz) = vra[i];
        *(s16x8*)((char*)Vb2[p^1] + (row0+32*i)*128 + swz) = vrb[i];
      }
      __syncthreads();
      p ^= 1;
    }
  }

  // ---- epilogue ----
  float inv = 1.0f/lsum;
  int ii = __builtin_bit_cast(int, inv);
  #pragma unroll
  for (int r=0;r<16;r++){
    int cr = (r&3)+8*(r>>2)+4*hi;
    float sc = __builtin_bit_cast(float, __builtin_amdgcn_ds_bpermute(cr<<2, ii));
    int qg = i0 + w*32 + cr;
    unsigned short* op = O + ((size_t)(b*NQ + qg))*1024 + h*64 + q5;
    op[0]  = f2bf(o0[r]*sc);
    op[32] = f2bf(o1[r]*sc);
  }
}

extern "C" void kernel_launch(void* const* d_in, const int* in_sizes, int n_in,
                              void* d_out, int out_size, void* d_ws, size_t ws_size,
                              hipStream_t stream){
  const float* x   = (const float*)d_in[0];
  const float* ctx = (const float*)d_in[1];
  const float* g1  = (const float*)d_in[3];
  const float* b1  = (const float*)d_in[4];
  const float* g2  = (const float*)d_in[5];
  const float* b2  = (const float*)d_in[6];
  const float* Wq  = (const float*)d_in[7];
  const float* Wkv = (const float*)d_in[8];
  const float* Wo  = (const float*)d_in[9];
  const float* bo  = (const float*)d_in[10];
  float* out = (float*)d_out;

  unsigned short* xn  = (unsigned short*)d_ws;
  unsigned short* cn  = xn  + (size_t)BB*NQ*DIMM;
  unsigned short* qbf = cn  + (size_t)BB*NCTX*DIMM;
  unsigned short* kbf = qbf + (size_t)BB*NQ*1024;
  unsigned short* vbf = kbf + (size_t)BB*NKV*1024;
  unsigned short* oa  = vbf + (size_t)BB*NKV*1024;
  unsigned short* wpk = oa  + (size_t)BB*NQ*1024;
  unsigned short* woT = wpk + (size_t)3072*1024;
  unsigned short* vT  = xn;   // reuse xn+cn region after QKV GEMMs: [2*16*64][4096]

  wconv3_kernel<<<dim3(128,32),256,0,stream>>>(Wq, Wkv, Wo, wpk, woT);
  ln2_kernel<<<dim3(BB*(NQ+NCTX)),256,0,stream>>>(x, ctx, g1, b1, g2, b2, xn, cn);
  gemm_kernel<0><<<dim3(3072/BN,(BB*NQ)/BM),256,0,stream>>>(
      xn, wpk, qbf, kbf, vbf, nullptr, nullptr, 1024);
  gemm_kernel<1><<<dim3(2048/BN,(BB*NCTX)/BM),256,0,stream>>>(
      cn, wpk + (size_t)1024*1024, kbf, vbf, nullptr, nullptr, nullptr, 1024);
  vtrans_kernel<<<dim3(64,16,2),256,0,stream>>>(vbf, vT);
  attn_kernel<<<dim3(512),256,0,stream>>>(qbf, kbf, vT, oa);
  gemm_kernel<2><<<dim3(1024/BN,(BB*NQ)/BM),256,0,stream>>>(
      oa, woT, nullptr, nullptr, nullptr, out, bo, 1024);
}

// Round 7
// 343.525 us; speedup vs baseline: 1.0969x; 1.0969x over previous
//
#include <hip/hip_runtime.h>
#include <hip/hip_bf16.h>

#define BB 2
#define NQ 2048
#define NCTX 2048
#define DIMM 1024
#define NH 16
#define DH 64
#define NKV 4096
#define LOG2E 1.44269504088896340736f

typedef float f32x4  __attribute__((ext_vector_type(4)));
typedef float f32x16 __attribute__((ext_vector_type(16)));
typedef short s16x8  __attribute__((ext_vector_type(8)));
typedef unsigned u32x4 __attribute__((ext_vector_type(4)));

__device__ __forceinline__ unsigned short f2bf(float f){
  __hip_bfloat16 h = __float2bfloat16(f);
  return *reinterpret_cast<unsigned short*>(&h);
}

// v_cvt_pk_bf16_f32: D.lo16 = bf16(a), D.hi16 = bf16(b) (RNE), HW-verified R5
__device__ __forceinline__ unsigned pk2(float a, float b){
  unsigned r;
  asm("v_cvt_pk_bf16_f32 %0, %1, %2" : "=v"(r) : "v"(a), "v"(b));
  return r;
}

// async global->LDS, 16B per lane; LDS base must be wave-uniform
__device__ __forceinline__ void cp16(const void* g, void* l){
  __builtin_amdgcn_global_load_lds(
    (const __attribute__((address_space(1))) unsigned int*)(unsigned long long)g,
    (__attribute__((address_space(3))) unsigned int*)(unsigned int)(unsigned long long)l,
    16, 0, 0);
}

__device__ __forceinline__ f32x16 zero16(){
  f32x16 z;
  #pragma unroll
  for (int i=0;i<16;i++) z[i]=0.f;
  return z;
}

// ---------------- merged LayerNorm (x rows then ctx rows) ----------------
__global__ __launch_bounds__(256) void ln2_kernel(const float* __restrict__ x,
    const float* __restrict__ ctx,
    const float* __restrict__ g1, const float* __restrict__ b1,
    const float* __restrict__ g2, const float* __restrict__ b2,
    unsigned short* __restrict__ xn, unsigned short* __restrict__ cn){
  int row = blockIdx.x;
  const float *src, *g, *bta; unsigned short* dst; int r;
  if (row < BB*NQ){ src = x;   g = g1; bta = b1; dst = xn; r = row; }
  else            { src = ctx; g = g2; bta = b2; dst = cn; r = row - BB*NQ; }
  int t = threadIdx.x;
  const float4* xr = (const float4*)(src + (size_t)r*DIMM);
  float4 v = xr[t];
  float s  = v.x+v.y+v.z+v.w;
  float sq = v.x*v.x+v.y*v.y+v.z*v.z+v.w*v.w;
  #pragma unroll
  for (int off=32; off>0; off>>=1){ s += __shfl_down(s, off); sq += __shfl_down(sq, off); }
  __shared__ float red[8];
  int w = t>>6;
  if ((t&63)==0){ red[w]=s; red[w+4]=sq; }
  __syncthreads();
  s  = red[0]+red[1]+red[2]+red[3];
  sq = red[4]+red[5]+red[6]+red[7];
  float mean = s*(1.0f/DIMM);
  float var  = sq*(1.0f/DIMM) - mean*mean;
  float rstd = rsqrtf(var + 1e-5f);
  float4 gv = ((const float4*)g)[t];
  float4 bv = ((const float4*)bta)[t];
  unsigned int o0 = f2bf((v.x-mean)*rstd*gv.x + bv.x);
  unsigned int o1 = f2bf((v.y-mean)*rstd*gv.y + bv.y);
  unsigned int o2 = f2bf((v.z-mean)*rstd*gv.z + bv.z);
  unsigned int o3 = f2bf((v.w-mean)*rstd*gv.w + bv.w);
  uint2 pk; pk.x = o0 | (o1<<16); pk.y = o2 | (o3<<16);
  ((uint2*)(dst + (size_t)r*DIMM))[t] = pk;
}

// ---------- merged weight transpose+convert (Wq | Wkv | Wo) ----------
__global__ __launch_bounds__(256) void wconv3_kernel(const float* __restrict__ Wq,
    const float* __restrict__ Wkv, const float* __restrict__ Wo,
    unsigned short* __restrict__ wpk, unsigned short* __restrict__ woT){
  __shared__ float tile[32][33];
  int bx = blockIdx.x;                 // 0..127
  const float* src; unsigned short* dst; int N; float scale; int nb;
  if (bx < 32)      { src=Wq;  dst=wpk;                      N=1024; scale=0.125f; nb=bx; }
  else if (bx < 96) { src=Wkv; dst=wpk + (size_t)1024*1024;  N=2048; scale=1.0f;   nb=bx-32; }
  else              { src=Wo;  dst=woT;                      N=1024; scale=1.0f;   nb=bx-96; }
  int n0 = nb*32, k0 = blockIdx.y*32;
  int c = threadIdx.x & 31, r0 = threadIdx.x >> 5;
  #pragma unroll
  for (int i=0;i<4;i++){
    int r = r0 + i*8;
    tile[r][c] = src[(size_t)(k0+r)*N + n0 + c];
  }
  __syncthreads();
  #pragma unroll
  for (int i=0;i<4;i++){
    int r = r0 + i*8;
    dst[(size_t)(n0+r)*1024 + k0 + c] = f2bf(tile[c][r]*scale);
  }
}

// ---------------- bf16 GEMM: C = A[M][K] * BT[N][K]^T ----------------
#define BM 128
#define BN 128
#define BK 64
template<int MODE>
__global__ __launch_bounds__(256) void gemm_kernel(
    const unsigned short* __restrict__ A,
    const unsigned short* __restrict__ BT,
    unsigned short* __restrict__ D0,
    unsigned short* __restrict__ D1,
    unsigned short* __restrict__ D2,
    float* __restrict__ FO,
    const float* __restrict__ bias,
    int K){
  __shared__ unsigned short As[BM*BK];
  __shared__ unsigned short Bs[BN*BK];
  int t = threadIdx.x;
  int w = t>>6, l = t&63, lr = l&15, lg = l>>4;
  int wm = w>>1, wn = w&1;
  const unsigned short* Ab = A  + (size_t)(blockIdx.y*BM)*K;
  const unsigned short* Bb = BT + (size_t)(blockIdx.x*BN)*K;
  f32x4 acc[4][4];
  #pragma unroll
  for (int i=0;i<4;i++)
    #pragma unroll
    for (int j=0;j<4;j++) acc[i][j] = (f32x4){0.f,0.f,0.f,0.f};
  int nk = K >> 6;
  for (int kt=0; kt<nk; ++kt){
    __syncthreads();
    #pragma unroll
    for (int q=0;q<4;q++){
      int row = w*32 + q*8 + (l>>3);
      size_t go = (size_t)row*K + kt*64 + (l&7)*8;
      cp16(Ab + go, &As[(w*32+q*8)*64]);
      cp16(Bb + go, &Bs[(w*32+q*8)*64]);
    }
    __syncthreads();
    #pragma unroll
    for (int kk=0;kk<2;kk++){
      s16x8 af[4], bfr[4];
      #pragma unroll
      for (int mf=0;mf<4;mf++) af[mf]  = *(const s16x8*)&As[(wm*64+mf*16+lr)*64 + kk*32 + lg*8];
      #pragma unroll
      for (int nf=0;nf<4;nf++) bfr[nf] = *(const s16x8*)&Bs[(wn*64+nf*16+lr)*64 + kk*32 + lg*8];
      #pragma unroll
      for (int mf=0;mf<4;mf++)
        #pragma unroll
        for (int nf=0;nf<4;nf++)
          acc[mf][nf] = __builtin_amdgcn_mfma_f32_16x16x32_bf16(af[mf], bfr[nf], acc[mf][nf], 0,0,0);
    }
  }
  int rbase = blockIdx.y*BM + wm*64;
  int cbase = blockIdx.x*BN + wn*64;
  #pragma unroll
  for (int mf=0;mf<4;mf++){
    #pragma unroll
    for (int nf=0;nf<4;nf++){
      #pragma unroll
      for (int rr=0;rr<4;rr++){
        int r = rbase + mf*16 + lg*4 + rr;
        int c = cbase + nf*16 + lr;
        float val = acc[mf][nf][rr];
        if (MODE == 2){
          FO[(size_t)r*1024 + c] = val + bias[c];
        } else if (MODE == 0){
          int b = r >> 11, rl = r & 2047;
          unsigned short bv = f2bf(val);
          if (c < 1024)      D0[((size_t)b*NQ + rl)*1024 + c] = bv;
          else if (c < 2048) D1[((size_t)b*NKV + NCTX + rl)*1024 + (c-1024)] = bv;
          else               D2[((size_t)b*NKV + NCTX + rl)*1024 + (c-2048)] = bv;
        } else {
          int b = r >> 11, rl = r & 2047;
          unsigned short bv = f2bf(val);
          if (c < 1024) D0[((size_t)b*NKV + rl)*1024 + c] = bv;
          else          D1[((size_t)b*NKV + rl)*1024 + (c-1024)] = bv;
        }
      }
    }
  }
}

// ---------- V transpose: V[b][j][h*64+d] -> VT[(b*16+h)*64+d][j] (bf16) ----------
__global__ __launch_bounds__(256) void vtrans_kernel(const unsigned short* __restrict__ V,
    unsigned short* __restrict__ VT){
  __shared__ unsigned short tl[64][72];
  int j0 = blockIdx.x*64, h = blockIdx.y, b = blockIdx.z;
  int tid = threadIdx.x;
  int r = tid>>3, c8 = (tid&7)*8;
  const unsigned short* src = V + ((size_t)(b*NKV + j0))*1024 + h*64;
  #pragma unroll
  for (int p=0;p<2;p++){
    int row = r + p*32;
    *(s16x8*)&tl[row][c8] = *(const s16x8*)(src + (size_t)row*1024 + c8);
  }
  __syncthreads();
  unsigned short* dst = VT + ((size_t)(b*16+h)*64)*4096 + j0;
  #pragma unroll
  for (int p=0;p<2;p++){
    int d = r + p*32;
    s16x8 o;
    #pragma unroll
    for (int e=0;e<8;e++) o[e] = (short)tl[c8+e][d];
    *(s16x8*)(dst + (size_t)d*4096 + c8) = o;
  }
}

// ---------------- flash attention (causal-prefix), 32x32 swapped-QK ----------------
// R7: exact R5 structure restored (KVBLK=64, 2 barriers/tile, T12 pack, tree reduce,
// setprio). R6's KVBLK=128 dbuf regressed (L2 sharing loss, occupancy drop).
__global__ __launch_bounds__(256) void attn_kernel(
    const unsigned short* __restrict__ Q,
    const unsigned short* __restrict__ Kg,
    const unsigned short* __restrict__ VT,
    unsigned short* __restrict__ O){
  __shared__ unsigned short Ks[64*64];
  __shared__ unsigned short Vs[64*64];
  int bx = blockIdx.x;
  int qb = 15 - (bx >> 5);          // longest (most KV tiles) first
  int hb = bx & 31;
  int h = hb & 15, b = hb >> 4;
  int i0 = qb*128;
  int tid = threadIdx.x;
  int w = tid>>6, l = tid&63;
  int q5 = l&31, hi = l>>5;

  int row0 = tid>>3, sl = tid&7;
  const unsigned short* Kb = Kg + (size_t)b*NKV*1024 + h*64;       // [j][1024]
  const unsigned short* Vb = VT + ((size_t)(b*16+h)*64)*4096;      // [d][4096]
  size_t kg0 = (size_t)row0*1024 + sl*8;
  size_t kg1 = kg0 + (size_t)32*1024;
  size_t vg0 = (size_t)row0*4096 + sl*8;
  size_t vg1 = vg0 + (size_t)32*4096;
  int sw0 = row0*128      + ((sl*16) ^ ((row0&7)<<4));
  int sw1 = (row0+32)*128 + ((sl*16) ^ ((row0&7)<<4));

  const unsigned short* Qr = Q + ((size_t)(b*NQ + i0 + w*32 + q5))*1024 + h*64 + hi*8;
  s16x8 qf[4];
  #pragma unroll
  for (int t=0;t<4;t++) qf[t] = *(const s16x8*)(Qr + t*16);

  f32x16 o0 = zero16(), o1 = zero16();
  float mref = -1e30f, m2 = 0.f, lsum = 0.f;

  int nkb = (NCTX + i0 + 128) >> 6;
  s16x8 kr0 = *(const s16x8*)(Kb + kg0);
  s16x8 kr1 = *(const s16x8*)(Kb + kg1);
  s16x8 vr0 = *(const s16x8*)(Vb + vg0);
  s16x8 vr1 = *(const s16x8*)(Vb + vg1);

  for (int kb=0; kb<nkb; ++kb){
    int j0 = kb*64;
    __syncthreads();
    *(s16x8*)((char*)Ks + sw0) = kr0;
    *(s16x8*)((char*)Ks + sw1) = kr1;
    *(s16x8*)((char*)Vs + sw0) = vr0;
    *(s16x8*)((char*)Vs + sw1) = vr1;
    if (kb+1 < nkb){
      size_t ko = (size_t)(kb+1)*64*1024;
      int vo = (kb+1)*64;
      kr0 = *(const s16x8*)(Kb + ko + kg0);
      kr1 = *(const s16x8*)(Kb + ko + kg1);
      vr0 = *(const s16x8*)(Vb + vo + vg0);
      vr1 = *(const s16x8*)(Vb + vo + vg1);
    }
    __syncthreads();

    f32x16 s0 = zero16(), s1 = zero16();
    __builtin_amdgcn_s_setprio(1);
    #pragma unroll
    for (int t=0;t<4;t++){
      int xo = (t*32 + hi*16) ^ ((q5&7)<<4);
      s16x8 kf0 = *(const s16x8*)((char*)Ks + q5*128 + xo);
      s16x8 kf1 = *(const s16x8*)((char*)Ks + (q5+32)*128 + xo);
      s0 = __builtin_amdgcn_mfma_f32_32x32x16_bf16(kf0, qf[t], s0, 0,0,0);
      s1 = __builtin_amdgcn_mfma_f32_32x32x16_bf16(kf1, qf[t], s1, 0,0,0);
    }
    __builtin_amdgcn_s_setprio(0);

    if (j0 + 63 > NCTX + i0 + w*32){
      int iq = i0 + w*32 + q5;
      #pragma unroll
      for (int r=0;r<16;r++){
        int j = j0 + ((r&3)+8*(r>>2)+4*hi);
        if (j      > NCTX + iq) s0[r] = -1e30f;
        if (j + 32 > NCTX + iq) s1[r] = -1e30f;
      }
    }

    // ---- row max: 4 independent chains then combine ----
    float t0=-1e30f, t1=-1e30f, t2=-1e30f, t3=-1e30f;
    #pragma unroll
    for (int r=0;r<16;r+=4){
      t0 = fmaxf(t0, fmaxf(s0[r  ], s1[r  ]));
      t1 = fmaxf(t1, fmaxf(s0[r+1], s1[r+1]));
      t2 = fmaxf(t2, fmaxf(s0[r+2], s1[r+2]));
      t3 = fmaxf(t3, fmaxf(s0[r+3], s1[r+3]));
    }
    float pm = fmaxf(fmaxf(t0,t1), fmaxf(t2,t3));
    pm = fmaxf(pm, __shfl_xor(pm, 32));
    if (__any(pm - mref > 8.0f)){
      float mnew = fmaxf(mref, pm);
      float alpha = exp2f((mref - mnew)*LOG2E);
      mref = mnew; m2 = mnew*LOG2E;
      lsum *= alpha;
      int ai = __builtin_bit_cast(int, alpha);
      #pragma unroll
      for (int r=0;r<16;r++){
        int cr = (r&3)+8*(r>>2)+4*hi;
        float av = __builtin_bit_cast(float, __builtin_amdgcn_ds_bpermute(cr<<2, ai));
        o0[r] *= av; o1[r] *= av;
      }
    }
    // ---- exp with 4-way split accumulators ----
    float e0=0.f, e1=0.f, e2=0.f, e3=0.f;
    #pragma unroll
    for (int r=0;r<16;r+=4){
      float a0 = exp2f(fmaf(s0[r  ], LOG2E, -m2));
      float a1 = exp2f(fmaf(s0[r+1], LOG2E, -m2));
      float a2 = exp2f(fmaf(s0[r+2], LOG2E, -m2));
      float a3 = exp2f(fmaf(s0[r+3], LOG2E, -m2));
      float b0 = exp2f(fmaf(s1[r  ], LOG2E, -m2));
      float b1 = exp2f(fmaf(s1[r+1], LOG2E, -m2));
      float b2 = exp2f(fmaf(s1[r+2], LOG2E, -m2));
      float b3 = exp2f(fmaf(s1[r+3], LOG2E, -m2));
      s0[r]=a0; s0[r+1]=a1; s0[r+2]=a2; s0[r+3]=a3;
      s1[r]=b0; s1[r+1]=b1; s1[r+2]=b2; s1[r+3]=b3;
      e0 += a0 + b0; e1 += a1 + b1; e2 += a2 + b2; e3 += a3 + b3;
    }
    float ps = (e0+e1) + (e2+e3);
    ps += __shfl_xor(ps, 32);
    lsum += ps;

    // ---- T12: P -> bf16 A-fragments via cvt_pk + permlane32_swap (HW-proven R5) ----
    s16x8 pa[4];
    #pragma unroll
    for (int t=0;t<4;t++){
      const f32x16& pp = (t<2) ? s0 : s1;
      int B8 = (t&1)*8;
      unsigned u0 = pk2(pp[B8+0], pp[B8+1]);
      unsigned u1 = pk2(pp[B8+2], pp[B8+3]);
      unsigned v0 = pk2(pp[B8+4], pp[B8+5]);
      unsigned v1 = pk2(pp[B8+6], pp[B8+7]);
      asm("v_permlane32_swap_b32 %0, %1" : "+v"(u0), "+v"(v0));
      asm("v_permlane32_swap_b32 %0, %1" : "+v"(u1), "+v"(v1));
      pa[t] = __builtin_bit_cast(s16x8, (u32x4){u0, u1, v0, v1});
    }

    __builtin_amdgcn_s_setprio(1);
    #pragma unroll
    for (int t=0;t<4;t++){
      int xo = (t*32 + hi*16) ^ ((q5&7)<<4);
      s16x8 vb0 = *(const s16x8*)((char*)Vs + q5*128 + xo);
      s16x8 vb1 = *(const s16x8*)((char*)Vs + (q5+32)*128 + xo);
      o0 = __builtin_amdgcn_mfma_f32_32x32x16_bf16(pa[t], vb0, o0, 0,0,0);
      o1 = __builtin_amdgcn_mfma_f32_32x32x16_bf16(pa[t], vb1, o1, 0,0,0);
    }
    __builtin_amdgcn_s_setprio(0);
  }

  float inv = 1.0f/lsum;
  int ii = __builtin_bit_cast(int, inv);
  #pragma unroll
  for (int r=0;r<16;r++){
    int cr = (r&3)+8*(r>>2)+4*hi;
    float sc = __builtin_bit_cast(float, __builtin_amdgcn_ds_bpermute(cr<<2, ii));
    int qg = i0 + w*32 + cr;
    unsigned short* op = O + ((size_t)(b*NQ + qg))*1024 + h*64 + q5;
    op[0]  = f2bf(o0[r]*sc);
    op[32] = f2bf(o1[r]*sc);
  }
}

extern "C" void kernel_launch(void* const* d_in, const int* in_sizes, int n_in,
                              void* d_out, int out_size, void* d_ws, size_t ws_size,
                              hipStream_t stream){
  const float* x   = (const float*)d_in[0];
  const float* ctx = (const float*)d_in[1];
  const float* g1  = (const float*)d_in[3];
  const float* b1  = (const float*)d_in[4];
  const float* g2  = (const float*)d_in[5];
  const float* b2  = (const float*)d_in[6];
  const float* Wq  = (const float*)d_in[7];
  const float* Wkv = (const float*)d_in[8];
  const float* Wo  = (const float*)d_in[9];
  const float* bo  = (const float*)d_in[10];
  float* out = (float*)d_out;

  unsigned short* xn  = (unsigned short*)d_ws;
  unsigned short* cn  = xn  + (size_t)BB*NQ*DIMM;
  unsigned short* qbf = cn  + (size_t)BB*NCTX*DIMM;
  unsigned short* kbf = qbf + (size_t)BB*NQ*1024;
  unsigned short* vbf = kbf + (size_t)BB*NKV*1024;
  unsigned short* oa  = vbf + (size_t)BB*NKV*1024;
  unsigned short* wpk = oa  + (size_t)BB*NQ*1024;
  unsigned short* woT = wpk + (size_t)3072*1024;
  unsigned short* vT  = xn;   // reuse xn+cn region after QKV GEMMs: [2*16*64][4096]

  wconv3_kernel<<<dim3(128,32),256,0,stream>>>(Wq, Wkv, Wo, wpk, woT);
  ln2_kernel<<<dim3(BB*(NQ+NCTX)),256,0,stream>>>(x, ctx, g1, b1, g2, b2, xn, cn);
  gemm_kernel<0><<<dim3(3072/BN,(BB*NQ)/BM),256,0,stream>>>(
      xn, wpk, qbf, kbf, vbf, nullptr, nullptr, 1024);
  gemm_kernel<1><<<dim3(2048/BN,(BB*NCTX)/BM),256,0,stream>>>(
      cn, wpk + (size_t)1024*1024, kbf, vbf, nullptr, nullptr, nullptr, 1024);
  vtrans_kernel<<<dim3(64,16,2),256,0,stream>>>(vbf, vT);
  attn_kernel<<<dim3(512),256,0,stream>>>(qbf, kbf, vT, oa);
  gemm_kernel<2><<<dim3(1024/BN,(BB*NQ)/BM),256,0,stream>>>(
      oa, woT, nullptr, nullptr, nullptr, out, bo, 1024);
}